// Round 6
// baseline (627.924 us; speedup 1.0000x reference)
//
#include <hip/hip_runtime.h>

// Mandelbrot escape-time counts — matching a CONTRACTION-ENABLED host golden.
//
// ELIMINATION LADDER (all semantics-verified, arithmetic-only differences):
//   R1 f32, gfx950 backend free-fuse:        absmax 187
//   R2 f32, unfused mag/nr + fma next_imag:  absmax 201
//   R3 f32, fully unfused (pragma):          absmax 201
//   R4 f32, fully unfused (INLINE ASM):      absmax 201   <- golden != pure f32
//   R5 f64, fully unfused (INLINE ASM):      absmax 197   <- golden != pure f64
// next_imag has only two f32 realizations (fused / unfused; the x2 is an
// exponent shift so the reassociated form == unfused). R2+R4 covered BOTH
// with unfused mag/next_real and both failed => the golden FUSES mag and/or
// next_real. That is precisely LLVM DAG contraction (XLA-CPU fast-math or a
// jitted-C numpy reference) and its deterministic pattern is:
//   zi2 = fl32(zi*zi)                        ; multi-use mul stays rounded
//   mag = fma(zr, zr, zi2)                   ; left mul fused into the add
//   nr  = fl32( fma(zr, zr, -zi2) + cr )     ; fsub->fma, then separate add
//   ni  = fma(2*zr, zi, ci)                  ; single-use outer mul fused
// x86 FMA and v_fma_f32 are both IEEE-754 single-rounded: bit-identical.
// All ops pinned with inline asm so no compile flag can re-associate.
//
// Loop semantics (== reference): check z_0..z_255; first check s with
// mag>=4 -> count s; survive all -> 256 (ref's 257th check writes 256 = init).
// act is sticky-zero; (NaN < 4) is false so escaped lanes never resurrect;
// the count add has no mul operand so it cannot be contracted.

#define MAX_ITERS 256

__device__ __forceinline__ float mul32(float a, float b) {
    float d; asm("v_mul_f32 %0, %1, %2" : "=v"(d) : "v"(a), "v"(b)); return d;
}
__device__ __forceinline__ float add32(float a, float b) {
    float d; asm("v_add_f32 %0, %1, %2" : "=v"(d) : "v"(a), "v"(b)); return d;
}
__device__ __forceinline__ float fma32(float a, float b, float c) {
    float d; asm("v_fma_f32 %0, %1, %2, %3" : "=v"(d) : "v"(a), "v"(b), "v"(c)); return d;
}
__device__ __forceinline__ float fma32_negc(float a, float b, float c) {
    float d; asm("v_fma_f32 %0, %1, %2, -%3" : "=v"(d) : "v"(a), "v"(b), "v"(c)); return d;
}

__global__ __launch_bounds__(256) void mandelbrot_kernel(
    const float* __restrict__ c_real,
    const float* __restrict__ c_imag,
    float* __restrict__ out,
    int n)
{
    int i = blockIdx.x * blockDim.x + threadIdx.x;
    if (i >= n) return;

    const float cr = c_real[i];
    const float ci = c_imag[i];

    float zr = cr;
    float zi = ci;
    float act = 1.0f;   // sticky: 1.0 while not yet escaped
    float cnt = 0.0f;   // accumulates one per surviving check = escape step

    #pragma unroll 8
    for (int s = 0; s < MAX_ITERS; ++s) {
        const float zi2 = mul32(zi, zi);            // fl32(zi^2), multi-use
        const float mag = fma32(zr, zr, zi2);       // fma(zr,zr, zi2): fused escape metric
        act = (mag < 4.0f) ? act : 0.0f;            // sticky escape, NaN-safe
        cnt = cnt + act;                            // exact small-int add
        const float t   = fma32_negc(zr, zr, zi2);  // fma(zr,zr, -zi2)
        const float nr  = add32(t, cr);             // + cr, separately rounded
        const float t2  = add32(zr, zr);            // 2*zr, exact
        zi = fma32(t2, zi, ci);                     // fma(2zr, zi, ci)
        zr = nr;
    }

    out[i] = cnt;  // 256.0 if never escaped
}

extern "C" void kernel_launch(void* const* d_in, const int* in_sizes, int n_in,
                              void* d_out, int out_size, void* d_ws, size_t ws_size,
                              hipStream_t stream)
{
    const float* c_real = (const float*)d_in[0];
    const float* c_imag = (const float*)d_in[1];
    float* out = (float*)d_out;
    const int n = in_sizes[0];  // 4096*4096

    const int block = 256;
    const int grid = (n + block - 1) / block;
    mandelbrot_kernel<<<grid, block, 0, stream>>>(c_real, c_imag, out, n);
}